// Round 4
// baseline (37.028 us; speedup 1.0000x reference)
//
#include <hip/hip_runtime.h>
#include <math.h>

// Problem constants (reference: B=16, C=256, H=80, W=80, K=3, ALPHA=0.1, EPS=1e-7)
#define L_LEN 6400        // H*W
#define NROWS 4096        // B*C
#define C_CH 256
#define TPB 256           // 4 waves; each wave owns one full row
#define CHUNKS 25         // 25 chunks x 256 floats (64 lanes x float4) = 6400
// log2(0.9), 0.9^256 (f32)
#define LOG2_DECAY_F -0.15200309f
#define C256 1.93237e-12f

typedef float v4f __attribute__((ext_vector_type(4)));

// Zero-LDS design: lane-interleaved ownership. Lane l, chunk j owns elements
// p = 256j + 4l + q (q=0..3). Loads AND stores are lane-contiguous dwordx4
// (1 KB per wave-instruction, full 128B lines -> nt stores cannot amplify).
// Absolute EMA weight factors: 0.1 * 0.9^(256j) * 0.9^(4l) * 0.9^q, so the
// cumsum is: per-lane geometric prefix (4 fma) -> wave scan of partials
// (6 shfl) -> scalar cross-chunk carry S. No LDS, no barriers; waves fully
// independent (4 rows per 256-thread block).
__global__ __launch_bounds__(TPB, 4) void ema_attn_kernel(
    const float* __restrict__ x,
    const float* __restrict__ conv_w,   // [C,1,3]
    const float* __restrict__ conv_b,   // [C]
    float* __restrict__ out)
{
    const int t    = threadIdx.x;
    const int lane = t & 63;
    const int wid  = t >> 6;
    const int row  = blockIdx.x * 4 + wid;   // grid = NROWS/4
    const int c    = row & (C_CH - 1);

    const float w0   = conv_w[c * 3 + 0];
    const float w1   = conv_w[c * 3 + 1];
    const float w2   = conv_w[c * 3 + 2];
    const float bias = conv_b[c];

    const long rowbase = (long)row * L_LEN;
    const v4f* gin  = (const v4f*)(x + rowbase);    // [64*j + lane]
    v4f*       gout = (v4f*)(out + rowbase);

    // al = 0.1 * 0.9^(4*lane) * 0.9^(256*j); updated by *= 0.9^256 per chunk.
    float al = 0.1f * exp2f((float)(4 * lane) * LOG2_DECAY_F);
    float S  = 0.f;          // weighted cumsum carry across chunks
    float pl = 0.f;          // x[256j - 1] (prev chunk's last element), for lane 0

    v4f cur = gin[lane];     // chunk 0
    v4f nxt;

#pragma unroll
    for (int j = 0; j < CHUNKS; ++j) {
        if (j < CHUNKS - 1) nxt = gin[64 * (j + 1) + lane];

        // per-lane geometric prefix over own 4 elements (relative weights 0.9^q)
        const float p0 = cur.x;
        const float p1 = fmaf(cur.y, 0.9f,   p0);
        const float p2 = fmaf(cur.z, 0.81f,  p1);
        const float p3 = fmaf(cur.w, 0.729f, p2);

        // wave inclusive scan of absolute-weighted lane partials
        const float y = al * p3;
        float inc = y;
#pragma unroll
        for (int off = 1; off < 64; off <<= 1) {
            float n = __shfl_up(inc, off, 64);
            if (lane >= off) inc += n;
        }
        const float excl  = (S + inc) - y;        // S_j + exclusive-within-chunk
        const float total = __shfl(inc, 63, 64);

        // conv neighbor elements across lane/chunk boundaries
        float m = __shfl_up(cur.w, 1, 64);        // x[p-1] for q=0
        if (lane == 0) m = pl;                    // prev chunk's last (0 at j=0)
        float d = __shfl_down(cur.x, 1, 64);      // x[p+1] for q=3
        const float nf = (j < CHUNKS - 1) ? __shfl(nxt.x, 0, 64) : 0.f;
        if (lane == 63) d = nf;                   // next chunk's first (0 at j=24)
        pl = __shfl(cur.w, 63, 64);               // carry for next chunk

        // outputs: ema + conv + residual  (cd = 1 - 0.9^(p+1) + eps)
        v4f o;
        {   // q=0
            const float cum  = fmaf(al, p0, excl);
            const float cd   = fmaf(-al, 9.0f, 1.0f) + 1e-7f;
            const float ema  = cum * __builtin_amdgcn_rcpf(cd);
            const float conv = fmaf(w0, m, fmaf(w1, cur.x, fmaf(w2, cur.y, bias)));
            o.x = ema + conv + cur.x;
        }
        {   // q=1
            const float cum  = fmaf(al, p1, excl);
            const float cd   = fmaf(-al, 8.1f, 1.0f) + 1e-7f;
            const float ema  = cum * __builtin_amdgcn_rcpf(cd);
            const float conv = fmaf(w0, cur.x, fmaf(w1, cur.y, fmaf(w2, cur.z, bias)));
            o.y = ema + conv + cur.y;
        }
        {   // q=2
            const float cum  = fmaf(al, p2, excl);
            const float cd   = fmaf(-al, 7.29f, 1.0f) + 1e-7f;
            const float ema  = cum * __builtin_amdgcn_rcpf(cd);
            const float conv = fmaf(w0, cur.y, fmaf(w1, cur.z, fmaf(w2, cur.w, bias)));
            o.z = ema + conv + cur.z;
        }
        {   // q=3
            const float cum  = fmaf(al, p3, excl);
            const float cd   = fmaf(-al, 6.561f, 1.0f) + 1e-7f;
            const float ema  = cum * __builtin_amdgcn_rcpf(cd);
            const float conv = fmaf(w0, cur.z, fmaf(w1, cur.w, fmaf(w2, d, bias)));
            o.w = ema + conv + cur.w;
        }
        __builtin_nontemporal_store(o, gout + 64 * j + lane);

        S  += total;      // cross-chunk cumsum carry (only serial dependency)
        al *= C256;       // advance absolute weight by 0.9^256
        cur = nxt;
    }
}

extern "C" void kernel_launch(void* const* d_in, const int* in_sizes, int n_in,
                              void* d_out, int out_size, void* d_ws, size_t ws_size,
                              hipStream_t stream) {
    const float* x      = (const float*)d_in[0];
    const float* conv_w = (const float*)d_in[1];
    const float* conv_b = (const float*)d_in[2];
    float* out          = (float*)d_out;
    ema_attn_kernel<<<NROWS / 4, TPB, 0, stream>>>(x, conv_w, conv_b, out);
}

// Round 5
// 36.456 us; speedup vs baseline: 1.0157x; 1.0157x over previous
//
#include <hip/hip_runtime.h>
#include <math.h>

// Problem constants (reference: B=16, C=256, H=80, W=80, K=3, ALPHA=0.1, EPS=1e-7)
#define L_LEN 6400        // H*W
#define NROWS 4096        // B*C
#define C_CH 256
#define TPB 256           // 4 waves; each wave owns one full row
#define CHUNKS 25         // 25 chunks x 256 floats (64 lanes x float4) = 6400
// log2(0.9), 0.9^256 (f32)
#define LOG2_DECAY_F -0.15200309f
#define C256 1.93237e-12f

typedef float v4f __attribute__((ext_vector_type(4)));

// Zero-LDS design: lane-interleaved ownership. Lane l, chunk j owns elements
// p = 256j + 4l + q (q=0..3). Loads AND stores are lane-contiguous dwordx4
// (1 KB per wave-instruction, full 128B lines). R5 single-variable change:
// PLAIN stores instead of nontemporal -- every prior round used nt; four
// structurally different kernels all converged at ~36-37us (5.8 TB/s logical),
// so the store cache policy is the last untested axis on the bandwidth wall.
__global__ __launch_bounds__(TPB, 4) void ema_attn_kernel(
    const float* __restrict__ x,
    const float* __restrict__ conv_w,   // [C,1,3]
    const float* __restrict__ conv_b,   // [C]
    float* __restrict__ out)
{
    const int t    = threadIdx.x;
    const int lane = t & 63;
    const int wid  = t >> 6;
    const int row  = blockIdx.x * 4 + wid;   // grid = NROWS/4
    const int c    = row & (C_CH - 1);

    const float w0   = conv_w[c * 3 + 0];
    const float w1   = conv_w[c * 3 + 1];
    const float w2   = conv_w[c * 3 + 2];
    const float bias = conv_b[c];

    const long rowbase = (long)row * L_LEN;
    const v4f* gin  = (const v4f*)(x + rowbase);    // [64*j + lane]
    v4f*       gout = (v4f*)(out + rowbase);

    // al = 0.1 * 0.9^(4*lane) * 0.9^(256*j); updated by *= 0.9^256 per chunk.
    float al = 0.1f * exp2f((float)(4 * lane) * LOG2_DECAY_F);
    float S  = 0.f;          // weighted cumsum carry across chunks
    float pl = 0.f;          // x[256j - 1] (prev chunk's last element), for lane 0

    v4f cur = gin[lane];     // chunk 0
    v4f nxt;

#pragma unroll
    for (int j = 0; j < CHUNKS; ++j) {
        if (j < CHUNKS - 1) nxt = gin[64 * (j + 1) + lane];

        // per-lane geometric prefix over own 4 elements (relative weights 0.9^q)
        const float p0 = cur.x;
        const float p1 = fmaf(cur.y, 0.9f,   p0);
        const float p2 = fmaf(cur.z, 0.81f,  p1);
        const float p3 = fmaf(cur.w, 0.729f, p2);

        // wave inclusive scan of absolute-weighted lane partials
        const float y = al * p3;
        float inc = y;
#pragma unroll
        for (int off = 1; off < 64; off <<= 1) {
            float n = __shfl_up(inc, off, 64);
            if (lane >= off) inc += n;
        }
        const float excl  = (S + inc) - y;        // S_j + exclusive-within-chunk
        const float total = __shfl(inc, 63, 64);

        // conv neighbor elements across lane/chunk boundaries
        float m = __shfl_up(cur.w, 1, 64);        // x[p-1] for q=0
        if (lane == 0) m = pl;                    // prev chunk's last (0 at j=0)
        float d = __shfl_down(cur.x, 1, 64);      // x[p+1] for q=3
        const float nf = (j < CHUNKS - 1) ? __shfl(nxt.x, 0, 64) : 0.f;
        if (lane == 63) d = nf;                   // next chunk's first (0 at j=24)
        pl = __shfl(cur.w, 63, 64);               // carry for next chunk

        // outputs: ema + conv + residual  (cd = 1 - 0.9^(p+1) + eps)
        v4f o;
        {   // q=0
            const float cum  = fmaf(al, p0, excl);
            const float cd   = fmaf(-al, 9.0f, 1.0f) + 1e-7f;
            const float ema  = cum * __builtin_amdgcn_rcpf(cd);
            const float conv = fmaf(w0, m, fmaf(w1, cur.x, fmaf(w2, cur.y, bias)));
            o.x = ema + conv + cur.x;
        }
        {   // q=1
            const float cum  = fmaf(al, p1, excl);
            const float cd   = fmaf(-al, 8.1f, 1.0f) + 1e-7f;
            const float ema  = cum * __builtin_amdgcn_rcpf(cd);
            const float conv = fmaf(w0, cur.x, fmaf(w1, cur.y, fmaf(w2, cur.z, bias)));
            o.y = ema + conv + cur.y;
        }
        {   // q=2
            const float cum  = fmaf(al, p2, excl);
            const float cd   = fmaf(-al, 7.29f, 1.0f) + 1e-7f;
            const float ema  = cum * __builtin_amdgcn_rcpf(cd);
            const float conv = fmaf(w0, cur.y, fmaf(w1, cur.z, fmaf(w2, cur.w, bias)));
            o.z = ema + conv + cur.z;
        }
        {   // q=3
            const float cum  = fmaf(al, p3, excl);
            const float cd   = fmaf(-al, 6.561f, 1.0f) + 1e-7f;
            const float ema  = cum * __builtin_amdgcn_rcpf(cd);
            const float conv = fmaf(w0, cur.z, fmaf(w1, cur.w, fmaf(w2, d, bias)));
            o.w = ema + conv + cur.w;
        }
        gout[64 * j + lane] = o;    // plain store: allocate in L2/MALL, lazy drain

        S  += total;      // cross-chunk cumsum carry (only serial dependency)
        al *= C256;       // advance absolute weight by 0.9^256
        cur = nxt;
    }
}

extern "C" void kernel_launch(void* const* d_in, const int* in_sizes, int n_in,
                              void* d_out, int out_size, void* d_ws, size_t ws_size,
                              hipStream_t stream) {
    const float* x      = (const float*)d_in[0];
    const float* conv_w = (const float*)d_in[1];
    const float* conv_b = (const float*)d_in[2];
    float* out          = (float*)d_out;
    ema_attn_kernel<<<NROWS / 4, TPB, 0, stream>>>(x, conv_w, conv_b, out);
}